// Round 6
// baseline (362.274 us; speedup 1.0000x reference)
//
#include <hip/hip_runtime.h>
#include <stdint.h>

// Problem constants (fixed by the reference)
#define CHARS   10000
#define KPAD    10240   // K padded to multiple of 64
#define HIDDEN  1024
#define OUTPUT  100
#define OPAD    128     // padded output cols for coalesced W2T
#define BATCH   4096
#define MAXLEN  2048
#define NTILES  8       // HIDDEN/128 == number of XCDs (the lucky constant)

typedef __bf16 bf16_t;
typedef __bf16 bf16x8 __attribute__((ext_vector_type(8)));
typedef float  f32x4  __attribute__((ext_vector_type(4)));

// ---------------------------------------------------------------------------
// async global->LDS 16B copy (wave-uniform base + lane*16 dest)
// ---------------------------------------------------------------------------
__device__ __forceinline__ void gload_lds16(const void* g, void* l) {
    __builtin_amdgcn_global_load_lds(
        (const __attribute__((address_space(1))) uint32_t*)g,
        (__attribute__((address_space(3))) uint32_t*)l,
        16, 0, 0);
}

// ---------------------------------------------------------------------------
// W1 (HIDDEN x CHARS fp32) -> W1b (HIDDEN x KPAD bf16), zero-padded cols.
// ---------------------------------------------------------------------------
__global__ void k_w1bf16(const float* __restrict__ W1, bf16_t* __restrict__ W1b) {
    int c = blockIdx.x * 256 + threadIdx.x;   // 0..KPAD-1
    int h = blockIdx.y;                       // 0..HIDDEN-1
    float v = (c < CHARS) ? W1[(size_t)h * CHARS + c] : 0.0f;
    W1b[(size_t)h * KPAD + c] = (bf16_t)v;
}

// ---------------------------------------------------------------------------
// W2 (OUTPUT x HIDDEN fp32) -> W2T (HIDDEN x OPAD fp32), zero-padded cols.
// ---------------------------------------------------------------------------
__global__ void k_w2t(const float* __restrict__ W2, float* __restrict__ W2T) {
    int o = threadIdx.x;      // 0..127
    int k = blockIdx.x;       // 0..1023
    W2T[(size_t)k * OPAD + o] = (o < OUTPUT) ? W2[(size_t)o * HIDDEN + k] : 0.0f;
}

// ---------------------------------------------------------------------------
// hid pre-init with b1 (split-K GEMM atomically accumulates on top)
// ---------------------------------------------------------------------------
__global__ void k_hidinit(const float* __restrict__ b1, float* __restrict__ hid) {
    int h = blockIdx.y * 256 + threadIdx.x;   // 0..1023
    hid[(size_t)blockIdx.x * HIDDEN + h] = b1[h];
}

// ---------------------------------------------------------------------------
// Per-row histogram: one block per batch row. 40KB LDS uint32 counts.
// ---------------------------------------------------------------------------
__global__ void k_hist(const int* __restrict__ words, bf16_t* __restrict__ hist,
                       int rowStart) {
    __shared__ uint32_t h[KPAD];              // 40 KB
    const int tid = threadIdx.x;
    for (int i = tid; i < KPAD; i += 256) h[i] = 0u;
    __syncthreads();
    const int* w = words + (size_t)(rowStart + blockIdx.x) * MAXLEN;
    for (int i = tid; i < MAXLEN; i += 256)
        atomicAdd(&h[w[i]], 1u);
    __syncthreads();
    bf16_t* dst = hist + (size_t)blockIdx.x * KPAD;
    for (int i = tid; i < KPAD; i += 256)
        dst[i] = (bf16_t)(float)h[i];
}

// ---------------------------------------------------------------------------
// compute one BK=64 k-step from an LDS buffer pair (XOR-swizzled layout:
// LDS chunk c of row r holds global 16B-chunk c^(r&7); conflict-free, R2/R5).
// ---------------------------------------------------------------------------
__device__ __forceinline__ void compute_step(const bf16_t* As, const bf16_t* Bs,
                                             int wm, int wn, int fr, int qd,
                                             f32x4 acc[4][4]) {
#pragma unroll
    for (int kk = 0; kk < 64; kk += 32) {
        const int gc = (kk >> 3) + qd;        // global 16B-chunk index 0..7
        bf16x8 af[4], bq[4];
#pragma unroll
        for (int i = 0; i < 4; ++i) {
            const int R = wm + i * 16 + fr;
            af[i] = *(const bf16x8*)(As + R * 64 + ((gc ^ (R & 7)) * 8));
        }
#pragma unroll
        for (int j = 0; j < 4; ++j) {
            const int R = wn + j * 16 + fr;
            bq[j] = *(const bf16x8*)(Bs + R * 64 + ((gc ^ (R & 7)) * 8));
        }
#pragma unroll
        for (int i = 0; i < 4; ++i)
#pragma unroll
            for (int j = 0; j < 4; ++j)
                acc[i][j] = __builtin_amdgcn_mfma_f32_16x16x32_bf16(
                    af[i], bq[j], acc[i][j], 0, 0, 0);
    }
}

// ---------------------------------------------------------------------------
// bf16 MFMA GEMM, R5 pipeline + XCD-locality swizzle:
//   1D grid; ntile = blockIdx.x & 7. Under round-robin block->XCD dispatch
//   each XCD sees exactly ONE n-tile, so its B slice (128 x 10240 bf16 =
//   2.6 MB) stays L2-resident: B's L3<->L2 broadcast traffic (16x = 336 MB
//   per dispatch) collapses to one fill (21 MB). The R1-R5 invariant
//   ~126 us = 672 MB demand / ~5.3 TB/s fabric; this cuts demand ~2x.
//   128x128 tile, BK=64, double-buffered LDS, vmcnt(8)/lgkmcnt(0) barriers.
//   Split-K over slice -> fp32 atomicAdd into pre-initialized hid.
// ---------------------------------------------------------------------------
__global__ void __launch_bounds__(256)
k_gemm(const bf16_t* __restrict__ A, const bf16_t* __restrict__ Bt,
       float* __restrict__ hid, int mtiles, int ksteps_per_slice) {
    __shared__ __attribute__((aligned(16))) bf16_t As[2][128 * 64];  // 2x16 KB
    __shared__ __attribute__((aligned(16))) bf16_t Bs[2][128 * 64];  // 2x16 KB

    const int tid  = threadIdx.x;
    const int lane = tid & 63;
    const int wave = tid >> 6;

    // XCD-aware decode: n-tile pinned to (blockIdx.x % 8) == XCD id heuristic
    const int id   = blockIdx.x;
    const int nt   = id & (NTILES - 1);
    const int rest = id >> 3;
    const int mt   = rest % mtiles;
    const int sl   = rest / mtiles;
    const int m0 = mt * 128;
    const int n0 = nt * 128;
    const long kbeg = (long)sl * ksteps_per_slice * 64;
    const long kend = kbeg + (long)ksteps_per_slice * 64;

    // staging: thread covers rows srow+32i (i=0..3); source = global chunk
    // (tid&7)^(srow&7); dest forced to base + tid*16  => LDS(r,c) = g-chunk
    // c^(r&7). Conflict-free for both write and read (measured 0, R2/R5).
    const int srow = tid >> 3;                       // 0..31
    const int gch  = (tid & 7) ^ (srow & 7);
    const bf16_t* Ag = A  + (size_t)(m0 + srow) * KPAD + gch * 8;
    const bf16_t* Bg = Bt + (size_t)(n0 + srow) * KPAD + gch * 8;

    f32x4 acc[4][4] = {};
    const int wm = (wave & 1) * 64;       // wave's 64x64 sub-tile
    const int wn = (wave >> 1) * 64;
    const int fr = lane & 15;
    const int qd = lane >> 4;

    // prologue: fill buffer 0 with k-step kbeg (8 loads in flight)
#pragma unroll
    for (int i = 0; i < 4; ++i) {
        gload_lds16(Ag + (size_t)i * 32 * KPAD + kbeg, As[0] + i * 2048 + tid * 8);
        gload_lds16(Bg + (size_t)i * 32 * KPAD + kbeg, Bs[0] + i * 2048 + tid * 8);
    }

    int buf = 0;
    for (long k = kbeg; k < kend; k += 64) {
        // prefetch next k-step into the other buffer (wrap on final step so
        // the vmcnt(8) bookkeeping stays invariant; wrapped data is unused)
        const long kn = (k + 64 < kend) ? (k + 64) : kbeg;
        const int nb = buf ^ 1;
#pragma unroll
        for (int i = 0; i < 4; ++i) {
            gload_lds16(Ag + (size_t)i * 32 * KPAD + kn, As[nb] + i * 2048 + tid * 8);
            gload_lds16(Bg + (size_t)i * 32 * KPAD + kn, Bs[nb] + i * 2048 + tid * 8);
        }
        // wait: all but the 8 just-issued loads have landed (buf ready)
        asm volatile("s_waitcnt vmcnt(8)\n\ts_barrier" ::: "memory");
        compute_step(As[buf], Bs[buf], wm, wn, fr, qd, acc);
        // reads drained before anyone overwrites this buffer next iter
        asm volatile("s_waitcnt lgkmcnt(0)\n\ts_barrier" ::: "memory");
        buf = nb;
    }

    // epilogue: C/D layout col=lane&15, row=(lane>>4)*4+reg  [guide §3, m89]
    const int er = (lane >> 4) * 4;
    const int ec = lane & 15;
#pragma unroll
    for (int i = 0; i < 4; ++i) {
#pragma unroll
        for (int j = 0; j < 4; ++j) {
            float* dst = hid + (size_t)(m0 + wm + i * 16 + er) * HIDDEN
                             + (n0 + wn + j * 16 + ec);
#pragma unroll
            for (int r = 0; r < 4; ++r)
                atomicAdd(dst + (size_t)r * HIDDEN, acc[i][j][r]);
        }
    }
}

// ---------------------------------------------------------------------------
// out[b,o] = sum_k hid[b,k] * W2T[k,o] + b2[o]
// ---------------------------------------------------------------------------
__global__ void k_out(const float* __restrict__ hid, const float* __restrict__ W2T,
                      const float* __restrict__ b2, float* __restrict__ out) {
    const int tid = threadIdx.x;
    const int o4  = (tid & 31) * 4;
    const int rs  = tid >> 5;
    const int row = blockIdx.x * 8 + rs;
    const float* hrow = hid + (size_t)row * HIDDEN;
    f32x4 acc = {0.f, 0.f, 0.f, 0.f};
    for (int k0 = 0; k0 < HIDDEN; k0 += 4) {
        f32x4 hv = *(const f32x4*)(hrow + k0);
#pragma unroll
        for (int q = 0; q < 4; ++q) {
            f32x4 wv = *(const f32x4*)(W2T + (size_t)(k0 + q) * OPAD + o4);
            acc += hv[q] * wv;
        }
    }
    if (o4 < OUTPUT) {
        float* op = out + (size_t)row * OUTPUT + o4;
#pragma unroll
        for (int q = 0; q < 4; ++q)
            op[q] = acc[q] + b2[o4 + q];
    }
}

// ---------------------------------------------------------------------------
static inline int pick_split(int mtiles) {
    // target 512 blocks = one full residency round at 2 blocks/CU (64KB LDS);
    // S must divide 160 k-steps
    int target = 512 / (mtiles * NTILES);
    if (target < 1) target = 1;
    const int divs[12] = {160, 80, 40, 32, 20, 16, 10, 8, 5, 4, 2, 1};
    for (int i = 0; i < 12; ++i)
        if (divs[i] <= target) return divs[i];
    return 1;
}

extern "C" void kernel_launch(void* const* d_in, const int* in_sizes, int n_in,
                              void* d_out, int out_size, void* d_ws, size_t ws_size,
                              hipStream_t stream) {
    (void)in_sizes; (void)n_in; (void)out_size;
    const int*   words = (const int*)d_in[0];
    const float* W1    = (const float*)d_in[1];
    const float* b1    = (const float*)d_in[2];
    const float* W2    = (const float*)d_in[3];
    const float* b2    = (const float*)d_in[4];
    float* out = (float*)d_out;

    // workspace layout
    char* ws = (char*)d_ws;
    size_t off = 0;
    bf16_t* W1b  = (bf16_t*)(ws + off); off += (size_t)HIDDEN * KPAD * sizeof(bf16_t); // 21.0 MB
    float*  hid  = (float*) (ws + off); off += (size_t)BATCH * HIDDEN * sizeof(float); // 16.8 MB
    float*  W2T  = (float*) (ws + off); off += (size_t)HIDDEN * OPAD * sizeof(float);  // 0.5 MB
    bf16_t* histC = (bf16_t*)(ws + off);
    size_t rem = (ws_size > off) ? (ws_size - off) : 0;
    int chunkRows = (int)(rem / ((size_t)KPAD * sizeof(bf16_t)));
    chunkRows = (chunkRows / 128) * 128;
    if (chunkRows > BATCH) chunkRows = BATCH;
    if (chunkRows < 128)   chunkRows = 128;

    k_w1bf16<<<dim3(KPAD / 256, HIDDEN), dim3(256), 0, stream>>>(W1, W1b);
    k_w2t<<<dim3(HIDDEN), dim3(OPAD), 0, stream>>>(W2, W2T);
    k_hidinit<<<dim3(BATCH, HIDDEN / 256), dim3(256), 0, stream>>>(b1, hid);

    for (int r0 = 0; r0 < BATCH; r0 += chunkRows) {
        int rows = BATCH - r0;
        if (rows > chunkRows) rows = chunkRows;
        k_hist<<<dim3(rows), dim3(256), 0, stream>>>(words, histC, r0);
        int mtiles = rows / 128;
        int S = pick_split(mtiles);
        int ksteps = (KPAD / 64) / S;
        k_gemm<<<dim3(NTILES * mtiles * S), dim3(256), 0, stream>>>(
            histC, W1b, hid + (size_t)r0 * HIDDEN, mtiles, ksteps);
    }

    k_out<<<dim3(BATCH / 8), dim3(256), 0, stream>>>(hid, W2T, b2, out);
}

// Round 7
// 360.794 us; speedup vs baseline: 1.0041x; 1.0041x over previous
//
#include <hip/hip_runtime.h>
#include <stdint.h>

// Problem constants (fixed by the reference)
#define CHARS   10000
#define KPAD    10240   // K padded to multiple of 64
#define HIDDEN  1024
#define OUTPUT  100
#define OPAD    128     // padded output cols for coalesced W2T
#define BATCH   4096
#define MAXLEN  2048

#define TM      256     // GEMM tile rows
#define TN      256     // GEMM tile cols
#define THREADS 512     // 8 waves

typedef __bf16 bf16_t;
typedef __bf16 bf16x8 __attribute__((ext_vector_type(8)));
typedef float  f32x4  __attribute__((ext_vector_type(4)));

// ---------------------------------------------------------------------------
// async global->LDS 16B copy (wave-uniform base + lane*16 dest)
// ---------------------------------------------------------------------------
__device__ __forceinline__ void gload_lds16(const void* g, void* l) {
    __builtin_amdgcn_global_load_lds(
        (const __attribute__((address_space(1))) uint32_t*)g,
        (__attribute__((address_space(3))) uint32_t*)l,
        16, 0, 0);
}

// ---------------------------------------------------------------------------
// W1 (HIDDEN x CHARS fp32) -> W1b (HIDDEN x KPAD bf16), zero-padded cols.
// ---------------------------------------------------------------------------
__global__ void k_w1bf16(const float* __restrict__ W1, bf16_t* __restrict__ W1b) {
    int c = blockIdx.x * 256 + threadIdx.x;   // 0..KPAD-1
    int h = blockIdx.y;                       // 0..HIDDEN-1
    float v = (c < CHARS) ? W1[(size_t)h * CHARS + c] : 0.0f;
    W1b[(size_t)h * KPAD + c] = (bf16_t)v;
}

// ---------------------------------------------------------------------------
// W2 (OUTPUT x HIDDEN fp32) -> W2T (HIDDEN x OPAD fp32), zero-padded cols.
// ---------------------------------------------------------------------------
__global__ void k_w2t(const float* __restrict__ W2, float* __restrict__ W2T) {
    int o = threadIdx.x;      // 0..127
    int k = blockIdx.x;       // 0..1023
    W2T[(size_t)k * OPAD + o] = (o < OUTPUT) ? W2[(size_t)o * HIDDEN + k] : 0.0f;
}

// ---------------------------------------------------------------------------
// hid pre-init with b1 (split-K GEMM atomically accumulates on top)
// ---------------------------------------------------------------------------
__global__ void k_hidinit(const float* __restrict__ b1, float* __restrict__ hid) {
    int h = blockIdx.y * 256 + threadIdx.x;   // 0..1023
    hid[(size_t)blockIdx.x * HIDDEN + h] = b1[h];
}

// ---------------------------------------------------------------------------
// Per-row histogram: one block per batch row. 40KB LDS uint32 counts.
// ---------------------------------------------------------------------------
__global__ void k_hist(const int* __restrict__ words, bf16_t* __restrict__ hist,
                       int rowStart) {
    __shared__ uint32_t h[KPAD];              // 40 KB
    const int tid = threadIdx.x;
    for (int i = tid; i < KPAD; i += 256) h[i] = 0u;
    __syncthreads();
    const int* w = words + (size_t)(rowStart + blockIdx.x) * MAXLEN;
    for (int i = tid; i < MAXLEN; i += 256)
        atomicAdd(&h[w[i]], 1u);
    __syncthreads();
    bf16_t* dst = hist + (size_t)blockIdx.x * KPAD;
    for (int i = tid; i < KPAD; i += 256)
        dst[i] = (bf16_t)(float)h[i];
}

// ---------------------------------------------------------------------------
// compute one BK=64 k-step from a 256x64 LDS pair (XOR-swizzled layout:
// LDS chunk c of row r holds global 16B-chunk c^(r&7); conflict-free,
// measured 0 in R2/R5/R6). Wave-tile 64x128: acc[4][8].
// ---------------------------------------------------------------------------
__device__ __forceinline__ void compute_step(const bf16_t* As, const bf16_t* Bs,
                                             int wm, int wn, int fr, int qd,
                                             f32x4 acc[4][8]) {
#pragma unroll
    for (int kk = 0; kk < 64; kk += 32) {
        const int gc = (kk >> 3) + qd;        // global 16B-chunk index 0..7
        bf16x8 af[4], bq[8];
#pragma unroll
        for (int i = 0; i < 4; ++i) {
            const int R = wm + i * 16 + fr;
            af[i] = *(const bf16x8*)(As + R * 64 + ((gc ^ (R & 7)) * 8));
        }
#pragma unroll
        for (int j = 0; j < 8; ++j) {
            const int R = wn + j * 16 + fr;
            bq[j] = *(const bf16x8*)(Bs + R * 64 + ((gc ^ (R & 7)) * 8));
        }
#pragma unroll
        for (int i = 0; i < 4; ++i)
#pragma unroll
            for (int j = 0; j < 8; ++j)
                acc[i][j] = __builtin_amdgcn_mfma_f32_16x16x32_bf16(
                    af[i], bq[j], acc[i][j], 0, 0, 0);
    }
}

// ---------------------------------------------------------------------------
// bf16 MFMA GEMM, 256x256 tile (2x arithmetic intensity vs 128x128 — the
// R1-R6 invariant ~126us tracked staged-byte volume, so halve it):
//   512 threads / 8 waves, wave-tile 64x128, BK=64, double-buffered 128KB
//   LDS, global_load_lds width=16, vmcnt(8)/lgkmcnt(0) barrier pipeline.
//   Staged volume: 64KB per kstep for 8.4 MFLOP (128 FLOP/byte vs 64).
//   Split-K over blockIdx.z -> fp32 atomicAdd into pre-initialized hid.
// ---------------------------------------------------------------------------
__global__ void __launch_bounds__(THREADS)
k_gemm(const bf16_t* __restrict__ A, const bf16_t* __restrict__ Bt,
       float* __restrict__ hid, int ksteps_per_slice) {
    __shared__ __attribute__((aligned(16))) bf16_t As[2][TM * 64];  // 2x32 KB
    __shared__ __attribute__((aligned(16))) bf16_t Bs[2][TN * 64];  // 2x32 KB

    const int tid  = threadIdx.x;
    const int lane = tid & 63;
    const int wave = tid >> 6;            // 0..7
    const int m0 = blockIdx.x * TM;
    const int n0 = blockIdx.y * TN;
    const long kbeg = (long)blockIdx.z * ksteps_per_slice * 64;
    const long kend = kbeg + (long)ksteps_per_slice * 64;

    // staging: thread covers rows srow+64i (i=0..3) for A and B; source =
    // global chunk (tid&7)^(srow&7); DMA dest forced to base + tid*16
    // => LDS(r,c) = global chunk c^(r&7).
    const int srow = tid >> 3;                       // 0..63
    const int gch  = (tid & 7) ^ (srow & 7);
    const bf16_t* Ag = A  + (size_t)(m0 + srow) * KPAD + gch * 8;
    const bf16_t* Bg = Bt + (size_t)(n0 + srow) * KPAD + gch * 8;

    f32x4 acc[4][8] = {};
    const int wm = (wave & 3) * 64;       // 4 m-waves
    const int wn = (wave >> 2) * 128;     // 2 n-waves
    const int fr = lane & 15;
    const int qd = lane >> 4;

    // prologue: fill buffer 0 (8 loads in flight per thread)
#pragma unroll
    for (int i = 0; i < 4; ++i) {
        gload_lds16(Ag + (size_t)i * 64 * KPAD + kbeg, As[0] + i * 4096 + tid * 8);
        gload_lds16(Bg + (size_t)i * 64 * KPAD + kbeg, Bs[0] + i * 4096 + tid * 8);
    }

    int buf = 0;
    for (long k = kbeg; k < kend; k += 64) {
        // prefetch next k-step into the other buffer (wrap on final step so
        // the vmcnt(8) bookkeeping stays invariant; wrapped data is unused)
        const long kn = (k + 64 < kend) ? (k + 64) : kbeg;
        const int nb = buf ^ 1;
#pragma unroll
        for (int i = 0; i < 4; ++i) {
            gload_lds16(Ag + (size_t)i * 64 * KPAD + kn, As[nb] + i * 4096 + tid * 8);
            gload_lds16(Bg + (size_t)i * 64 * KPAD + kn, Bs[nb] + i * 4096 + tid * 8);
        }
        // wait: all but the 8 just-issued loads have landed (buf ready)
        asm volatile("s_waitcnt vmcnt(8)\n\ts_barrier" ::: "memory");
        compute_step(As[buf], Bs[buf], wm, wn, fr, qd, acc);
        // reads drained before anyone overwrites this buffer next iter
        asm volatile("s_waitcnt lgkmcnt(0)\n\ts_barrier" ::: "memory");
        buf = nb;
    }

    // epilogue: C/D layout col=lane&15, row=(lane>>4)*4+reg  [guide §3, m89]
    const int er = (lane >> 4) * 4;
    const int ec = lane & 15;
#pragma unroll
    for (int i = 0; i < 4; ++i) {
#pragma unroll
        for (int j = 0; j < 8; ++j) {
            float* dst = hid + (size_t)(m0 + wm + i * 16 + er) * HIDDEN
                             + (n0 + wn + j * 16 + ec);
#pragma unroll
            for (int r = 0; r < 4; ++r)
                atomicAdd(dst + (size_t)r * HIDDEN, acc[i][j][r]);
        }
    }
}

// ---------------------------------------------------------------------------
// out[b,o] = sum_k hid[b,k] * W2T[k,o] + b2[o]
// ---------------------------------------------------------------------------
__global__ void k_out(const float* __restrict__ hid, const float* __restrict__ W2T,
                      const float* __restrict__ b2, float* __restrict__ out) {
    const int tid = threadIdx.x;
    const int o4  = (tid & 31) * 4;
    const int rs  = tid >> 5;
    const int row = blockIdx.x * 8 + rs;
    const float* hrow = hid + (size_t)row * HIDDEN;
    f32x4 acc = {0.f, 0.f, 0.f, 0.f};
    for (int k0 = 0; k0 < HIDDEN; k0 += 4) {
        f32x4 hv = *(const f32x4*)(hrow + k0);
#pragma unroll
        for (int q = 0; q < 4; ++q) {
            f32x4 wv = *(const f32x4*)(W2T + (size_t)(k0 + q) * OPAD + o4);
            acc += hv[q] * wv;
        }
    }
    if (o4 < OUTPUT) {
        float* op = out + (size_t)row * OUTPUT + o4;
#pragma unroll
        for (int q = 0; q < 4; ++q)
            op[q] = acc[q] + b2[o4 + q];
    }
}

// ---------------------------------------------------------------------------
static inline int pick_split(int mtiles) {
    // target 256 blocks = one residency round at 1 block/CU (128 KB LDS);
    // S must divide 160 k-steps
    int target = 256 / (mtiles * (HIDDEN / TN));
    if (target < 1) target = 1;
    const int divs[12] = {160, 80, 40, 32, 20, 16, 10, 8, 5, 4, 2, 1};
    for (int i = 0; i < 12; ++i)
        if (divs[i] <= target) return divs[i];
    return 1;
}

extern "C" void kernel_launch(void* const* d_in, const int* in_sizes, int n_in,
                              void* d_out, int out_size, void* d_ws, size_t ws_size,
                              hipStream_t stream) {
    (void)in_sizes; (void)n_in; (void)out_size;
    const int*   words = (const int*)d_in[0];
    const float* W1    = (const float*)d_in[1];
    const float* b1    = (const float*)d_in[2];
    const float* W2    = (const float*)d_in[3];
    const float* b2    = (const float*)d_in[4];
    float* out = (float*)d_out;

    // workspace layout
    char* ws = (char*)d_ws;
    size_t off = 0;
    bf16_t* W1b  = (bf16_t*)(ws + off); off += (size_t)HIDDEN * KPAD * sizeof(bf16_t); // 21.0 MB
    float*  hid  = (float*) (ws + off); off += (size_t)BATCH * HIDDEN * sizeof(float); // 16.8 MB
    float*  W2T  = (float*) (ws + off); off += (size_t)HIDDEN * OPAD * sizeof(float);  // 0.5 MB
    bf16_t* histC = (bf16_t*)(ws + off);
    size_t rem = (ws_size > off) ? (ws_size - off) : 0;
    int chunkRows = (int)(rem / ((size_t)KPAD * sizeof(bf16_t)));
    chunkRows = (chunkRows / TM) * TM;
    if (chunkRows > BATCH) chunkRows = BATCH;
    if (chunkRows < TM)    chunkRows = TM;

    k_w1bf16<<<dim3(KPAD / 256, HIDDEN), dim3(256), 0, stream>>>(W1, W1b);
    k_w2t<<<dim3(HIDDEN), dim3(OPAD), 0, stream>>>(W2, W2T);
    k_hidinit<<<dim3(BATCH, HIDDEN / 256), dim3(256), 0, stream>>>(b1, hid);

    for (int r0 = 0; r0 < BATCH; r0 += chunkRows) {
        int rows = BATCH - r0;
        if (rows > chunkRows) rows = chunkRows;
        k_hist<<<dim3(rows), dim3(256), 0, stream>>>(words, histC, r0);
        int mtiles = rows / TM;
        int S = pick_split(mtiles);
        int ksteps = (KPAD / 64) / S;
        k_gemm<<<dim3(mtiles, HIDDEN / TN, S), dim3(THREADS), 0, stream>>>(
            histC, W1b, hid + (size_t)r0 * HIDDEN, ksteps);
    }

    k_out<<<dim3(BATCH / 8), dim3(256), 0, stream>>>(hid, W2T, b2, out);
}

// Round 8
// 356.823 us; speedup vs baseline: 1.0153x; 1.0111x over previous
//
#include <hip/hip_runtime.h>
#include <stdint.h>

// Problem constants (fixed by the reference)
#define CHARS   10000
#define KPAD    10240   // logical K (padded to multiple of 64; cols >= CHARS are zero)
#define KSTR    10368   // A/B row ALLOCATION stride: 20736 B == 256 mod 4096
                        // breaks L2/MALL/HBM channel aliasing (20480 == 0 mod 4096
                        // put all same-chunk rows on one channel group, clamping
                        // the DMA path at ~4 B/cyc/CU across R1-R7)
#define HIDDEN  1024
#define HSTR    1088    // hid row stride (4352 B == 256 mod 4096), same reason
#define OUTPUT  100
#define OPAD    128     // padded output cols for coalesced W2T
#define BATCH   4096
#define MAXLEN  2048

typedef __bf16 bf16_t;
typedef __bf16 bf16x8 __attribute__((ext_vector_type(8)));
typedef float  f32x4  __attribute__((ext_vector_type(4)));

// ---------------------------------------------------------------------------
// async global->LDS 16B copy (wave-uniform base + lane*16 dest)
// ---------------------------------------------------------------------------
__device__ __forceinline__ void gload_lds16(const void* g, void* l) {
    __builtin_amdgcn_global_load_lds(
        (const __attribute__((address_space(1))) uint32_t*)g,
        (__attribute__((address_space(3))) uint32_t*)l,
        16, 0, 0);
}

// ---------------------------------------------------------------------------
// W1 (HIDDEN x CHARS fp32) -> W1b (HIDDEN x KSTR bf16), zero-padded to KPAD.
// Cols KPAD..KSTR are never read (k-loop covers < KPAD only).
// ---------------------------------------------------------------------------
__global__ void k_w1bf16(const float* __restrict__ W1, bf16_t* __restrict__ W1b) {
    int c = blockIdx.x * 256 + threadIdx.x;   // 0..KPAD-1
    int h = blockIdx.y;                       // 0..HIDDEN-1
    float v = (c < CHARS) ? W1[(size_t)h * CHARS + c] : 0.0f;
    W1b[(size_t)h * KSTR + c] = (bf16_t)v;
}

// ---------------------------------------------------------------------------
// W2 (OUTPUT x HIDDEN fp32) -> W2T (HIDDEN x OPAD fp32), zero-padded cols.
// ---------------------------------------------------------------------------
__global__ void k_w2t(const float* __restrict__ W2, float* __restrict__ W2T) {
    int o = threadIdx.x;      // 0..127
    int k = blockIdx.x;       // 0..1023
    W2T[(size_t)k * OPAD + o] = (o < OUTPUT) ? W2[(size_t)o * HIDDEN + k] : 0.0f;
}

// ---------------------------------------------------------------------------
// hid pre-init with b1 (split-K GEMM atomically accumulates on top)
// ---------------------------------------------------------------------------
__global__ void k_hidinit(const float* __restrict__ b1, float* __restrict__ hid) {
    int h = blockIdx.y * 256 + threadIdx.x;   // 0..1023
    hid[(size_t)blockIdx.x * HSTR + h] = b1[h];
}

// ---------------------------------------------------------------------------
// Per-row histogram: one block per batch row. 40KB LDS uint32 counts.
// ---------------------------------------------------------------------------
__global__ void k_hist(const int* __restrict__ words, bf16_t* __restrict__ hist,
                       int rowStart) {
    __shared__ uint32_t h[KPAD];              // 40 KB
    const int tid = threadIdx.x;
    for (int i = tid; i < KPAD; i += 256) h[i] = 0u;
    __syncthreads();
    const int* w = words + (size_t)(rowStart + blockIdx.x) * MAXLEN;
    for (int i = tid; i < MAXLEN; i += 256)
        atomicAdd(&h[w[i]], 1u);
    __syncthreads();
    bf16_t* dst = hist + (size_t)blockIdx.x * KSTR;
    for (int i = tid; i < KPAD; i += 256)
        dst[i] = (bf16_t)(float)h[i];
}

// ---------------------------------------------------------------------------
// compute one BK=64 k-step from an LDS buffer pair (XOR-swizzled layout:
// LDS chunk c of row r holds global 16B-chunk c^(r&7); conflict-free,
// measured 0 in R2/R5/R6/R7).
// ---------------------------------------------------------------------------
__device__ __forceinline__ void compute_step(const bf16_t* As, const bf16_t* Bs,
                                             int wm, int wn, int fr, int qd,
                                             f32x4 acc[4][4]) {
#pragma unroll
    for (int kk = 0; kk < 64; kk += 32) {
        const int gc = (kk >> 3) + qd;        // global 16B-chunk index 0..7
        bf16x8 af[4], bq[4];
#pragma unroll
        for (int i = 0; i < 4; ++i) {
            const int R = wm + i * 16 + fr;
            af[i] = *(const bf16x8*)(As + R * 64 + ((gc ^ (R & 7)) * 8));
        }
#pragma unroll
        for (int j = 0; j < 4; ++j) {
            const int R = wn + j * 16 + fr;
            bq[j] = *(const bf16x8*)(Bs + R * 64 + ((gc ^ (R & 7)) * 8));
        }
#pragma unroll
        for (int i = 0; i < 4; ++i)
#pragma unroll
            for (int j = 0; j < 4; ++j)
                acc[i][j] = __builtin_amdgcn_mfma_f32_16x16x32_bf16(
                    af[i], bq[j], acc[i][j], 0, 0, 0);
    }
}

// ---------------------------------------------------------------------------
// bf16 MFMA GEMM (R5 body, strides de-aliased):
//   128x128 tile, BK=64, double-buffered LDS, global_load_lds width=16,
//   vmcnt(8)/lgkmcnt(0) barrier pipeline.
//   Split-K over blockIdx.z -> fp32 atomicAdd into pre-initialized hid.
// ---------------------------------------------------------------------------
__global__ void __launch_bounds__(256)
k_gemm(const bf16_t* __restrict__ A, const bf16_t* __restrict__ Bt,
       float* __restrict__ hid, int ksteps_per_slice) {
    __shared__ __attribute__((aligned(16))) bf16_t As[2][128 * 64];  // 2x16 KB
    __shared__ __attribute__((aligned(16))) bf16_t Bs[2][128 * 64];  // 2x16 KB

    const int tid  = threadIdx.x;
    const int lane = tid & 63;
    const int wave = tid >> 6;
    const int m0 = blockIdx.x * 128;
    const int n0 = blockIdx.y * 128;
    const long kbeg = (long)blockIdx.z * ksteps_per_slice * 64;
    const long kend = kbeg + (long)ksteps_per_slice * 64;

    // staging: thread covers rows srow+32i (i=0..3); source = global chunk
    // (tid&7)^(srow&7); DMA dest forced to base + tid*16 => LDS(r,c) holds
    // global chunk c^(r&7). Conflict-free write+read (measured 0).
    const int srow = tid >> 3;                       // 0..31
    const int gch  = (tid & 7) ^ (srow & 7);
    const bf16_t* Ag = A  + (size_t)(m0 + srow) * KSTR + gch * 8;
    const bf16_t* Bg = Bt + (size_t)(n0 + srow) * KSTR + gch * 8;

    f32x4 acc[4][4] = {};
    const int wm = (wave & 1) * 64;       // wave's 64x64 sub-tile
    const int wn = (wave >> 1) * 64;
    const int fr = lane & 15;
    const int qd = lane >> 4;

    // prologue: fill buffer 0 with k-step kbeg (8 loads in flight)
#pragma unroll
    for (int i = 0; i < 4; ++i) {
        gload_lds16(Ag + (size_t)i * 32 * KSTR + kbeg, As[0] + i * 2048 + tid * 8);
        gload_lds16(Bg + (size_t)i * 32 * KSTR + kbeg, Bs[0] + i * 2048 + tid * 8);
    }

    int buf = 0;
    for (long k = kbeg; k < kend; k += 64) {
        // prefetch next k-step into the other buffer (wrap on final step so
        // the vmcnt(8) bookkeeping stays invariant; wrapped data is unused)
        const long kn = (k + 64 < kend) ? (k + 64) : kbeg;
        const int nb = buf ^ 1;
#pragma unroll
        for (int i = 0; i < 4; ++i) {
            gload_lds16(Ag + (size_t)i * 32 * KSTR + kn, As[nb] + i * 2048 + tid * 8);
            gload_lds16(Bg + (size_t)i * 32 * KSTR + kn, Bs[nb] + i * 2048 + tid * 8);
        }
        // wait: all but the 8 just-issued loads have landed (buf ready)
        asm volatile("s_waitcnt vmcnt(8)\n\ts_barrier" ::: "memory");
        compute_step(As[buf], Bs[buf], wm, wn, fr, qd, acc);
        // reads drained before anyone overwrites this buffer next iter
        asm volatile("s_waitcnt lgkmcnt(0)\n\ts_barrier" ::: "memory");
        buf = nb;
    }

    // epilogue: C/D layout col=lane&15, row=(lane>>4)*4+reg  [guide §3, m89]
    const int er = (lane >> 4) * 4;
    const int ec = lane & 15;
#pragma unroll
    for (int i = 0; i < 4; ++i) {
#pragma unroll
        for (int j = 0; j < 4; ++j) {
            float* dst = hid + (size_t)(m0 + wm + i * 16 + er) * HSTR
                             + (n0 + wn + j * 16 + ec);
#pragma unroll
            for (int r = 0; r < 4; ++r)
                atomicAdd(dst + (size_t)r * HSTR, acc[i][j][r]);
        }
    }
}

// ---------------------------------------------------------------------------
// out[b,o] = sum_k hid[b,k] * W2T[k,o] + b2[o]
// ---------------------------------------------------------------------------
__global__ void k_out(const float* __restrict__ hid, const float* __restrict__ W2T,
                      const float* __restrict__ b2, float* __restrict__ out) {
    const int tid = threadIdx.x;
    const int o4  = (tid & 31) * 4;
    const int rs  = tid >> 5;
    const int row = blockIdx.x * 8 + rs;
    const float* hrow = hid + (size_t)row * HSTR;
    f32x4 acc = {0.f, 0.f, 0.f, 0.f};
    for (int k0 = 0; k0 < HIDDEN; k0 += 4) {
        f32x4 hv = *(const f32x4*)(hrow + k0);
#pragma unroll
        for (int q = 0; q < 4; ++q) {
            f32x4 wv = *(const f32x4*)(W2T + (size_t)(k0 + q) * OPAD + o4);
            acc += hv[q] * wv;
        }
    }
    if (o4 < OUTPUT) {
        float* op = out + (size_t)row * OUTPUT + o4;
#pragma unroll
        for (int q = 0; q < 4; ++q)
            op[q] = acc[q] + b2[o4 + q];
    }
}

// ---------------------------------------------------------------------------
static inline int pick_split(int mtiles) {
    // target 512 blocks = one residency round at 2 blocks/CU (64KB LDS);
    // S must divide 160 k-steps
    int target = 512 / (mtiles * 8);
    if (target < 1) target = 1;
    const int divs[12] = {160, 80, 40, 32, 20, 16, 10, 8, 5, 4, 2, 1};
    for (int i = 0; i < 12; ++i)
        if (divs[i] <= target) return divs[i];
    return 1;
}

extern "C" void kernel_launch(void* const* d_in, const int* in_sizes, int n_in,
                              void* d_out, int out_size, void* d_ws, size_t ws_size,
                              hipStream_t stream) {
    (void)in_sizes; (void)n_in; (void)out_size;
    const int*   words = (const int*)d_in[0];
    const float* W1    = (const float*)d_in[1];
    const float* b1    = (const float*)d_in[2];
    const float* W2    = (const float*)d_in[3];
    const float* b2    = (const float*)d_in[4];
    float* out = (float*)d_out;

    // workspace layout (de-aliased strides)
    char* ws = (char*)d_ws;
    size_t off = 0;
    bf16_t* W1b  = (bf16_t*)(ws + off); off += (size_t)HIDDEN * KSTR * sizeof(bf16_t); // 21.2 MB
    float*  hid  = (float*) (ws + off); off += (size_t)BATCH * HSTR * sizeof(float);   // 17.8 MB
    float*  W2T  = (float*) (ws + off); off += (size_t)HIDDEN * OPAD * sizeof(float);  // 0.5 MB
    bf16_t* histC = (bf16_t*)(ws + off);
    size_t rem = (ws_size > off) ? (ws_size - off) : 0;
    int chunkRows = (int)(rem / ((size_t)KSTR * sizeof(bf16_t)));
    chunkRows = (chunkRows / 128) * 128;
    if (chunkRows > BATCH) chunkRows = BATCH;
    if (chunkRows < 128)   chunkRows = 128;

    k_w1bf16<<<dim3(KPAD / 256, HIDDEN), dim3(256), 0, stream>>>(W1, W1b);
    k_w2t<<<dim3(HIDDEN), dim3(OPAD), 0, stream>>>(W2, W2T);
    k_hidinit<<<dim3(BATCH, HIDDEN / 256), dim3(256), 0, stream>>>(b1, hid);

    for (int r0 = 0; r0 < BATCH; r0 += chunkRows) {
        int rows = BATCH - r0;
        if (rows > chunkRows) rows = chunkRows;
        k_hist<<<dim3(rows), dim3(256), 0, stream>>>(words, histC, r0);
        int mtiles = rows / 128;
        int S = pick_split(mtiles);
        int ksteps = (KPAD / 64) / S;
        k_gemm<<<dim3(mtiles, HIDDEN / 128, S), dim3(256), 0, stream>>>(
            histC, W1b, hid + (size_t)r0 * HSTR, ksteps);
    }

    k_out<<<dim3(BATCH / 8), dim3(256), 0, stream>>>(hid, W2T, b2, out);
}